// Round 13
// baseline (179.254 us; speedup 1.0000x reference)
//
#include <hip/hip_runtime.h>
#include <hip/hip_bf16.h>

// Problem constants
#define B_SZ 256
#define SDIM 1024
#define ADIM 512

#define NCHUNK 4             // chunks per block (= hq groups; K-quarter per block)
#define RING 3               // LDS ring depth (3 x 32 KB)

typedef __attribute__((ext_vector_type(8))) short bf16x8;
typedef __attribute__((ext_vector_type(4))) float f32x4;

__device__ __forceinline__ unsigned short f2bf(float x) {
  union { float f; unsigned u; } v; v.f = x;
  unsigned r = v.u + 0x7FFFu + ((v.u >> 16) & 1u);   // round-to-nearest-even
  return (unsigned short)(r >> 16);
}

__device__ __forceinline__ void gll16(const void* g, void* l) {
  __builtin_amdgcn_global_load_lds(
      (const __attribute__((address_space(1))) unsigned int*)g,
      (__attribute__((address_space(3))) unsigned int*)l, 16, 0, 0);
}

__device__ __forceinline__ unsigned cvtpk(float lo, float hi) {
  unsigned r;
  asm("v_cvt_pk_bf16_f32 %0, %1, %2" : "=v"(r) : "v"(lo), "v"(hi));
  return r;
}

// ---------------- Kernel 1: small MLPs + obsT fragment layout + cw2b dot --------
// obsT layout: [32 kc][4 g][256 b][8] bf16  (k = kc*32 + g*8 + j)
__global__ __launch_bounds__(128) void kprep(
    const float* __restrict__ obs,
    const float* __restrict__ task, const int* __restrict__ action,
    const float* __restrict__ we1, const float* __restrict__ be1,
    const float* __restrict__ we2, const float* __restrict__ be2,
    const float* __restrict__ aw1, const float* __restrict__ aw1b,
    const float* __restrict__ ab1, const float* __restrict__ ab1b,
    const float* __restrict__ ab2, const float* __restrict__ ab2b,
    const float* __restrict__ cw1, const float* __restrict__ cw1b,
    const float* __restrict__ cb1, const float* __restrict__ cb1b,
    const float* __restrict__ cb2, const float* __restrict__ cb2b,
    const float* __restrict__ cw2b,
    float* __restrict__ ws_ha, float* __restrict__ ws_hc,
    unsigned short* __restrict__ obsT,
    float* __restrict__ out)
{
  const int b = blockIdx.x, t = threadIdx.x;
  __shared__ float s_task[64], s_t1[64], s_z[64], s_hb[128], s_red[128];

  float dotc = 0.0f;
  {
    const int kc = t >> 2, g = t & 3;
    const float4* src = (const float4*)(obs + (size_t)b * SDIM + kc * 32 + g * 8);
    const float4* cbp = (const float4*)(cw2b + kc * 32 + g * 8);
    float4 x = src[0], y = src[1];
    float4 c0 = cbp[0], c1 = cbp[1];
    dotc = x.x * c0.x + x.y * c0.y + x.z * c0.z + x.w * c0.w
         + y.x * c1.x + y.y * c1.y + y.z * c1.z + y.w * c1.w;
    ushort4 u0, u1;
    u0.x = f2bf(x.x); u0.y = f2bf(x.y); u0.z = f2bf(x.z); u0.w = f2bf(x.w);
    u1.x = f2bf(y.x); u1.y = f2bf(y.y); u1.z = f2bf(y.z); u1.w = f2bf(y.w);
    ushort4* d = (ushort4*)(obsT + ((size_t)(kc * 4 + g) * 256 + b) * 8);
    d[0] = u0; d[1] = u1;
  }

  if (t < 64) s_task[t] = task[b * 64 + t];
  __syncthreads();
  if (t < 64) {
    float a = be1[t];
    for (int e = 0; e < 64; ++e) a += s_task[e] * we1[e * 64 + t];
    s_t1[t] = fmaxf(a, 0.0f);
  }
  __syncthreads();
  if (t < 64) {
    float a = be2[t];
    for (int e = 0; e < 64; ++e) a += s_t1[e] * we2[e * 64 + t];
    s_z[t] = fmaxf(a, 0.0f);
  }
  __syncthreads();
  {
    float a1 = aw1b[t], a2 = ab1b[t], a3 = cw1b[t], a4 = cb1b[t];
    for (int e = 0; e < 64; ++e) {
      const float zv = s_z[e];
      a1 += zv * aw1[e * 128 + t];
      a2 += zv * ab1[e * 128 + t];
      a3 += zv * cw1[e * 128 + t];
      a4 += zv * cb1[e * 128 + t];
    }
    ws_ha[b * 128 + t] = fmaxf(a1, 0.0f);
    s_hb[t] = fmaxf(a2, 0.0f);
    ws_hc[b * 128 + t] = fmaxf(a3, 0.0f);
    s_red[t] = fmaxf(a4, 0.0f) * cb2[t] + dotc;   // bv partial + cw2b.obs partial
  }
  __syncthreads();
  for (int o = t; o < ADIM; o += 128) {
    float a = ab2b[o];
    for (int h = 0; h < 128; ++h) a += s_hb[h] * ab2[h * ADIM + o];
    out[b * ADIM + o] = a;
  }
  for (int s = 64; s > 0; s >>= 1) {
    __syncthreads();
    if (t < s) s_red[t] += s_red[t + s];
  }
  if (t == 0) {
    out[131840 + b] = s_red[0] + cb2b[0];      // v partial; critic blocks add rest
    out[131072 + b] = (float)action[b];        // action as float
  }
}

// ---------------- Kernel 2: producer/consumer, 1KB-contiguous burst streaming ------
// Chunk = [32 rows][256 k] f32 (32 KB). Producer gll16 = ONE row x 1 KB contiguous
// (16B-slot XOR within 128B lines). Consumers: MFMA, A from L2 obsT, acc[4][8].
__global__ __launch_bounds__(512, 1) void khyper(
    const unsigned short* __restrict__ obsT,
    const float* __restrict__ aw2, const float* __restrict__ aw2b,
    const float* __restrict__ cw2,
    const float* __restrict__ ws_ha, const float* __restrict__ ws_hc,
    float* __restrict__ d_out)
{
  __shared__ __align__(16) char ring[RING * 32768];  // 96 KB
  __shared__ unsigned sync[20];    // [0..15]=flags[4][4], [16..19]=done[4]

  const int tid = threadIdx.x, blk = blockIdx.x;
  const int wv = tid >> 6, lane = tid & 63;
  const int lrow = lane & 15, grp = lane >> 4;

  // Roles (small blocks FIRST for makespan): 0..15 bias; 16..19 critic; 20.. actor
  int wtype, o0 = 0, kq;
  const char* rowbase;
  size_t rowstride;
  if (blk < 16) {
    wtype = 1; o0 = (blk >> 2) * 128; kq = blk & 3;
    rowbase = (const char*)(aw2b + (size_t)o0 * SDIM);
    rowstride = SDIM * 4;
  } else if (blk < 20) {
    wtype = 2; kq = blk - 16;
    rowbase = (const char*)cw2;
    rowstride = SDIM * 4;
  } else {
    const int idx = blk - 20;
    wtype = 0; o0 = idx >> 2; kq = idx & 3;
    rowbase = (const char*)(aw2 + (size_t)o0 * SDIM);
    rowstride = (size_t)ADIM * SDIM * 4;
  }
  const size_t kbyte = (size_t)kq * 1024;    // k-quarter (256 f32) byte offset

  if (tid < 20) sync[tid] = 0;
  __syncthreads();                            // only barrier in the kernel

  if (wv >= 4) {
    // ================= PRODUCER (waves 4..7) =================
    const int w = wv - 4;
#pragma unroll
    for (int c = 0; c < NCHUNK; ++c) {
      if (c >= RING) {
        while (*(volatile unsigned*)&sync[16 + c - RING] < 4u)
          __builtin_amdgcn_s_sleep(2);
      }
      char* dst = ring + (c % RING) * 32768 + w * 8192;
#pragma unroll
      for (int j = 0; j < 8; ++j) {
        const int row = c * 32 + w * 8 + j;
        const char* s = rowbase + (size_t)row * rowstride + kbyte
                      + (size_t)((lane ^ (row & 7)) << 4);
        gll16(s, dst + j * 1024);
      }
      if (c >= 1) {
        asm volatile("s_waitcnt vmcnt(8)" ::: "memory");
        *(volatile unsigned*)&sync[(c - 1) * 4 + w] = 1;
      }
    }
    asm volatile("s_waitcnt vmcnt(0)" ::: "memory");
    *(volatile unsigned*)&sync[(NCHUNK - 1) * 4 + w] = 1;
    return;
  }

  // ================= CONSUMER (waves 0..3) =================
  const int m0 = wv * 64;
  const unsigned short* pA0[4];
#pragma unroll
  for (int mf = 0; mf < 4; ++mf)
    pA0[mf] = obsT + (((size_t)(kq * 8) * 4 + grp) * 256 + (m0 + mf * 16 + lrow)) * 8;

  f32x4 acc[4][8];
#pragma unroll
  for (int mf = 0; mf < 4; ++mf)
#pragma unroll
    for (int nf = 0; nf < 8; ++nf) acc[mf][nf] = (f32x4)(0.0f);

#pragma unroll
  for (int c = 0; c < NCHUNK; ++c) {          // c == hq (rows c*32..c*32+31)
    {
      const volatile unsigned* fl = &sync[c * 4];
      while (fl[0] == 0u || fl[1] == 0u || fl[2] == 0u || fl[3] == 0u)
        __builtin_amdgcn_s_sleep(2);
    }
    __builtin_amdgcn_sched_barrier(0);
    const char* wb = ring + (c % RING) * 32768;
#pragma unroll
    for (int ks = 0; ks < 8; ++ks) {
      bf16x8 af[4];
#pragma unroll
      for (int mf = 0; mf < 4; ++mf)
        af[mf] = *(const bf16x8*)(pA0[mf] + (size_t)ks * 8192);
#pragma unroll
      for (int nfl = 0; nfl < 2; ++nfl) {
        const int row_local = nfl * 16 + lrow;
        const int s0 = (ks * 8 + grp * 2 + 0) ^ (row_local & 7);
        const int s1 = (ks * 8 + grp * 2 + 1) ^ (row_local & 7);
        f32x4 x = *(const f32x4*)(wb + row_local * 1024 + (s0 << 4));
        f32x4 y = *(const f32x4*)(wb + row_local * 1024 + (s1 << 4));
        union { bf16x8 v; unsigned u[4]; } p;
        p.u[0] = cvtpk(x[0], x[1]); p.u[1] = cvtpk(x[2], x[3]);
        p.u[2] = cvtpk(y[0], y[1]); p.u[3] = cvtpk(y[2], y[3]);
#pragma unroll
        for (int mf = 0; mf < 4; ++mf)
          acc[mf][c * 2 + nfl] =
              __builtin_amdgcn_mfma_f32_16x16x32_bf16(af[mf], p.v, acc[mf][c * 2 + nfl], 0, 0, 0);
      }
    }
    asm volatile("s_waitcnt lgkmcnt(0)" ::: "memory");
    if (lane == 0) atomicAdd(&sync[16 + c], 1u);
  }

  // ---- epilogue (r12-verified; rows = nf*16+lrow over 128) ----
  if (wtype == 1) {
#pragma unroll
    for (int mf = 0; mf < 4; ++mf) {
      const int b = m0 + mf * 16 + grp * 4;
#pragma unroll
      for (int nf = 0; nf < 8; ++nf) {
        const int col = o0 + nf * 16 + lrow;
#pragma unroll
        for (int r = 0; r < 4; ++r)
          atomicAdd(&d_out[(size_t)(b + r) * ADIM + col], acc[mf][nf][r]);
      }
    }
  } else {
    const float* hw = (wtype == 0) ? ws_ha : ws_hc;
#pragma unroll
    for (int mf = 0; mf < 4; ++mf) {
      const int b = m0 + mf * 16 + grp * 4;
      float val[4] = {0.f, 0.f, 0.f, 0.f};
#pragma unroll
      for (int nf = 0; nf < 8; ++nf) {
        const int h = nf * 16 + lrow;
#pragma unroll
        for (int r = 0; r < 4; ++r)
          val[r] += hw[(size_t)(b + r) * 128 + h] * acc[mf][nf][r];
      }
#pragma unroll
      for (int r = 0; r < 4; ++r) {
        float v = val[r];
        v += __shfl_xor(v, 1, 64);
        v += __shfl_xor(v, 2, 64);
        v += __shfl_xor(v, 4, 64);
        v += __shfl_xor(v, 8, 64);
        val[r] = v;
      }
      if (lrow == 0) {
#pragma unroll
        for (int r = 0; r < 4; ++r) {
          if (wtype == 0) atomicAdd(&d_out[(size_t)(b + r) * ADIM + o0], val[r]);
          else            atomicAdd(&d_out[131840 + b + r], val[r]);
        }
      }
    }
  }
}

// ---------------- Kernel 3: log_softmax / entropy / log_prob ----------------
__global__ __launch_bounds__(256) void kfinal(const int* __restrict__ action,
                                              float* __restrict__ d_out)
{
  const int b = blockIdx.x, t = threadIdx.x;
  const float* lrow = d_out + (size_t)b * ADIM;
  __shared__ float sM[4], sS[4], sT[4];

  const float x0 = lrow[t], x1 = lrow[t + 256];
  float m = fmaxf(x0, x1);
#pragma unroll
  for (int s = 1; s < 64; s <<= 1) m = fmaxf(m, __shfl_xor(m, s, 64));
  const int wv = t >> 6, ln = t & 63;
  if (ln == 0) sM[wv] = m;
  __syncthreads();
  m = fmaxf(fmaxf(sM[0], sM[1]), fmaxf(sM[2], sM[3]));

  const float d0 = x0 - m, d1 = x1 - m;
  const float e0 = expf(d0), e1 = expf(d1);
  float s1 = e0 + e1;
  float s2 = e0 * d0 + e1 * d1;
#pragma unroll
  for (int s = 1; s < 64; s <<= 1) {
    s1 += __shfl_xor(s1, s, 64);
    s2 += __shfl_xor(s2, s, 64);
  }
  if (ln == 0) { sS[wv] = s1; sT[wv] = s2; }
  __syncthreads();
  if (t == 0) {
    const float S = sS[0] + sS[1] + sS[2] + sS[3];
    const float T = sT[0] + sT[1] + sT[2] + sT[3];
    const float lnS = logf(S);
    const int a = action[b];
    d_out[131328 + b] = (lrow[a] - m) - lnS;   // log_prob
    d_out[131584 + b] = lnS - T / S;           // entropy
  }
}

extern "C" void kernel_launch(void* const* d_in, const int* in_sizes, int n_in,
                              void* d_out_v, int out_size, void* d_ws, size_t ws_size,
                              hipStream_t stream) {
  const float* obs   = (const float*)d_in[0];
  const float* task  = (const float*)d_in[1];
  const int*   action= (const int*)  d_in[2];
  const float* we1   = (const float*)d_in[3];
  const float* be1   = (const float*)d_in[4];
  const float* we2   = (const float*)d_in[5];
  const float* be2   = (const float*)d_in[6];
  const float* aw1   = (const float*)d_in[7];
  const float* aw1b  = (const float*)d_in[8];
  const float* aw2   = (const float*)d_in[9];
  const float* aw2b  = (const float*)d_in[10];
  const float* ab1   = (const float*)d_in[11];
  const float* ab1b  = (const float*)d_in[12];
  const float* ab2   = (const float*)d_in[13];
  const float* ab2b  = (const float*)d_in[14];
  const float* cw1   = (const float*)d_in[15];
  const float* cw1b  = (const float*)d_in[16];
  const float* cw2   = (const float*)d_in[17];
  const float* cw2b  = (const float*)d_in[18];
  const float* cb1   = (const float*)d_in[19];
  const float* cb1b  = (const float*)d_in[20];
  const float* cb2   = (const float*)d_in[21];
  const float* cb2b  = (const float*)d_in[22];
  float* out = (float*)d_out_v;
  float* ws_ha = (float*)d_ws;                        // [256][128] f32
  float* ws_hc = ws_ha + 256 * 128;                   // [256][128] f32
  unsigned short* obsT = (unsigned short*)(ws_hc + 256 * 128);  // [32][4][256][8] bf16

  kprep<<<256, 128, 0, stream>>>(obs, task, action, we1, be1, we2, be2, aw1, aw1b,
                                 ab1, ab1b, ab2, ab2b, cw1, cw1b, cb1, cb1b,
                                 cb2, cb2b, cw2b, ws_ha, ws_hc, obsT, out);
  // 16 bias + 4 critic (first) + 2048 actor (o x k-quarter)
  khyper<<<2068, 512, 0, stream>>>(obsT, aw2, aw2b, cw2, ws_ha, ws_hc, out);
  kfinal<<<256, 256, 0, stream>>>(action, out);
}

// Round 14
// 151.803 us; speedup vs baseline: 1.1808x; 1.1808x over previous
//
#include <hip/hip_runtime.h>
#include <hip/hip_bf16.h>

// Problem constants
#define B_SZ 256
#define SDIM 1024
#define ADIM 512

// khyper tile: 256-thread blocks, N-half = 80 rows, K-half = 512
#define BK 128
#define KSPLIT 2
#define KHALF (SDIM / KSPLIT)          // 512
#define NCHUNK (KHALF / BK)            // 4
#define ROWS 80                        // B-rows per block (half of 160)
#define PADB 136                       // ushort per LDS row (272B stride -> 2-way banks)
#define NSLOT 10                       // 80 rows * 32 float4 / 256 threads

typedef __attribute__((ext_vector_type(8))) short bf16x8;
typedef __attribute__((ext_vector_type(4))) float f32x4;

__device__ __forceinline__ unsigned short f2bf(float x) {
  union { float f; unsigned u; } v; v.f = x;
  unsigned r = v.u + 0x7FFFu + ((v.u >> 16) & 1u);   // round-to-nearest-even
  return (unsigned short)(r >> 16);
}

// ---------------- Kernel 1: small MLPs + obs->bf16 staging ----------------
__global__ __launch_bounds__(128) void kprep(
    const float* __restrict__ obs,
    const float* __restrict__ task, const int* __restrict__ action,
    const float* __restrict__ we1, const float* __restrict__ be1,
    const float* __restrict__ we2, const float* __restrict__ be2,
    const float* __restrict__ aw1, const float* __restrict__ aw1b,
    const float* __restrict__ ab1, const float* __restrict__ ab1b,
    const float* __restrict__ ab2, const float* __restrict__ ab2b,
    const float* __restrict__ cw1, const float* __restrict__ cw1b,
    const float* __restrict__ cb1, const float* __restrict__ cb1b,
    const float* __restrict__ cb2, const float* __restrict__ cb2b,
    float* __restrict__ ws_ha, float* __restrict__ ws_hc,
    unsigned short* __restrict__ ws_obs,
    float* __restrict__ out)
{
  const int b = blockIdx.x, t = threadIdx.x;
  __shared__ float s_task[64], s_t1[64], s_z[64], s_hb[128], s_red[128];

  // obs row b -> bf16 into ws_obs
  {
    const float4* orow = (const float4*)(obs + (size_t)b * SDIM);
    ushort4* wrow = (ushort4*)(ws_obs + (size_t)b * SDIM);
#pragma unroll
    for (int i = 0; i < 2; ++i) {
      const int idx = t + i * 128;
      float4 v = orow[idx];
      ushort4 u;
      u.x = f2bf(v.x); u.y = f2bf(v.y); u.z = f2bf(v.z); u.w = f2bf(v.w);
      wrow[idx] = u;
    }
  }

  if (t < 64) s_task[t] = task[b * 64 + t];
  __syncthreads();
  if (t < 64) {
    float a = be1[t];
    for (int e = 0; e < 64; ++e) a += s_task[e] * we1[e * 64 + t];
    s_t1[t] = fmaxf(a, 0.0f);
  }
  __syncthreads();
  if (t < 64) {
    float a = be2[t];
    for (int e = 0; e < 64; ++e) a += s_t1[e] * we2[e * 64 + t];
    s_z[t] = fmaxf(a, 0.0f);
  }
  __syncthreads();
  {
    float a1 = aw1b[t], a2 = ab1b[t], a3 = cw1b[t], a4 = cb1b[t];
    for (int e = 0; e < 64; ++e) {
      const float zv = s_z[e];
      a1 += zv * aw1[e * 128 + t];
      a2 += zv * ab1[e * 128 + t];
      a3 += zv * cw1[e * 128 + t];
      a4 += zv * cb1[e * 128 + t];
    }
    ws_ha[b * 128 + t] = fmaxf(a1, 0.0f);
    s_hb[t] = fmaxf(a2, 0.0f);
    ws_hc[b * 128 + t] = fmaxf(a3, 0.0f);
    s_red[t] = fmaxf(a4, 0.0f) * cb2[t];   // cb2 is [128,1]
  }
  __syncthreads();
  // ba -> staged into d_out logits slots (khyper atomically accumulates on top)
  for (int o = t; o < ADIM; o += 128) {
    float a = ab2b[o];
    for (int h = 0; h < 128; ++h) a += s_hb[h] * ab2[h * ADIM + o];
    out[b * ADIM + o] = a;
  }
  // bv reduction
  for (int s = 64; s > 0; s >>= 1) {
    __syncthreads();
    if (t < s) s_red[t] += s_red[t + s];
  }
  if (t == 0) {
    out[131840 + b] = s_red[0] + cb2b[0];      // partial v (bv); critic blocks add rest
    out[131072 + b] = (float)action[b];        // action as float
  }
}

// ---------------- Kernel 2: hypernet heavy GEMM + h-reduction ----------------
// r4 structure (best measured) + NON-TEMPORAL W loads (L3/L2 bypass attempt).
__global__ __launch_bounds__(256, 2) void khyper(
    const unsigned short* __restrict__ ws_obs,
    const float* __restrict__ aw2, const float* __restrict__ aw2b,
    const float* __restrict__ cw2, const float* __restrict__ cw2b,
    const float* __restrict__ ws_ha, const float* __restrict__ ws_hc,
    float* __restrict__ d_out)
{
  __shared__ unsigned short B_lds[ROWS * PADB];   // 21760 B
  __shared__ float logits_buf[B_SZ];

  const int tid = threadIdx.x;
  const int blk = blockIdx.x;
  const int kh   = blk & 1;            // K-half
  const int half = (blk >> 1) & 1;     // N-half (rows 0-79 / 80-159)
  const int col  = blk >> 2;           // 0..512 (512 = critic)
  const bool critic = (col == ADIM);
  const float* haW = critic ? ws_hc : ws_ha;
  const float* Wbase = critic ? cw2 : (aw2 + (size_t)col * SDIM);
  const size_t wstride = critic ? (size_t)SDIM : (size_t)ADIM * SDIM;
  const float* Bbias = critic ? cw2b : (aw2b + (size_t)col * SDIM);
  const int kbase = kh * KHALF;

  // Staging addressing: slot i covers row lr0+8i, 16B col c4*4
  const int lr0 = tid >> 5;            // 0..7
  const int c4  = tid & 31;            // 0..31 (x4 floats)
  const int g0  = half * ROWS + lr0;   // global B-row of slot 0
  const float* src0 = Wbase + (size_t)g0 * wstride + c4 * 4 + kbase;
  const size_t off8 = (size_t)8 * wstride;
  const float* biassrc = Bbias + c4 * 4 + kbase;
  const int soff0 = lr0 * PADB + c4 * 4;   // ushort units

  const int lane = tid & 63;
  const int wv = tid >> 6;             // 0..3 = M-group
  const int mbase = wv * 64;
  const int lrow = lane & 15;
  const int lk8 = (lane >> 4) * 8;

  const unsigned short* pA[4];
#pragma unroll
  for (int mf = 0; mf < 4; ++mf)
    pA[mf] = ws_obs + (size_t)(mbase + mf * 16 + lrow) * SDIM + kbase + lk8;

  f32x4 acc[4][5];
#pragma unroll
  for (int mf = 0; mf < 4; ++mf)
#pragma unroll
    for (int nf = 0; nf < 5; ++nf) acc[mf][nf] = (f32x4)(0.0f);

  f32x4 sreg[NSLOT];

  auto LOAD = [&](int c) {
    const int k0 = c * BK;
#pragma unroll
    for (int i = 0; i < NSLOT; ++i) {
      const int g = g0 + 8 * i;
      f32x4 v = (f32x4)(0.0f);
      if (g < 128)       v = __builtin_nontemporal_load((const f32x4*)(src0 + (size_t)i * off8 + k0));
      else if (g == 128) v = __builtin_nontemporal_load((const f32x4*)(biassrc + k0));
      sreg[i] = v;
    }
  };

  auto WRITE = [&]() {
#pragma unroll
    for (int i = 0; i < NSLOT; ++i) {
      ushort4 p;
      p.x = f2bf(sreg[i][0]); p.y = f2bf(sreg[i][1]);
      p.z = f2bf(sreg[i][2]); p.w = f2bf(sreg[i][3]);
      *(ushort4*)(&B_lds[soff0 + i * 8 * PADB]) = p;
    }
  };

  auto COMPUTE = [&](int c) {
    const int kg = c * BK;
#pragma unroll
    for (int kk = 0; kk < BK / 32; ++kk) {
      bf16x8 af[4];
#pragma unroll
      for (int mf = 0; mf < 4; ++mf)
        af[mf] = *(const bf16x8*)(pA[mf] + kg + kk * 32);
      bf16x8 bfr[5];
#pragma unroll
      for (int nf = 0; nf < 5; ++nf)
        bfr[nf] = *(const bf16x8*)(&B_lds[(nf * 16 + lrow) * PADB + kk * 32 + lk8]);
#pragma unroll
      for (int mf = 0; mf < 4; ++mf)
#pragma unroll
        for (int nf = 0; nf < 5; ++nf)
          acc[mf][nf] = __builtin_amdgcn_mfma_f32_16x16x32_bf16(af[mf], bfr[nf], acc[mf][nf], 0, 0, 0);
    }
  };

  const int rot = blk & 3;             // chunk-order rotation (channel desync)
  LOAD(rot);
#pragma unroll 1
  for (int c = 0; c < NCHUNK; ++c) {
    const int ce = (c + rot) & 3;
    WRITE();                                        // waits sreg (vmcnt), cvt, ds_write
    asm volatile("s_waitcnt lgkmcnt(0)" ::: "memory");
    __builtin_amdgcn_sched_barrier(0);
    __builtin_amdgcn_s_barrier();                   // raw: no vmcnt drain
    if (c + 1 < NCHUNK) LOAD((c + 1 + rot) & 3);    // next chunk in flight
    COMPUTE(ce);
    __builtin_amdgcn_sched_barrier(0);
    __builtin_amdgcn_s_barrier();                   // readers done before next WRITE
  }

  // Epilogue: partial logits[b] = sum_{h in this block} weight(h) * G[b,h]
  if (tid < B_SZ) logits_buf[tid] = 0.0f;
  __syncthreads();

  float val[4][4];
#pragma unroll
  for (int mf = 0; mf < 4; ++mf)
#pragma unroll
    for (int r = 0; r < 4; ++r) val[mf][r] = 0.0f;

#pragma unroll
  for (int nf = 0; nf < 5; ++nf) {
    const int hidx = half * ROWS + nf * 16 + lrow;
    if (hidx < 128) {
#pragma unroll
      for (int mf = 0; mf < 4; ++mf) {
        const int m0 = mbase + mf * 16 + ((lane >> 4) << 2);
#pragma unroll
        for (int r = 0; r < 4; ++r)
          val[mf][r] += haW[(m0 + r) * 128 + hidx] * acc[mf][nf][r];
      }
    } else if (hidx == 128) {   // bias row: weight 1
#pragma unroll
      for (int mf = 0; mf < 4; ++mf)
#pragma unroll
        for (int r = 0; r < 4; ++r) val[mf][r] += acc[mf][nf][r];
    }
  }

#pragma unroll
  for (int mf = 0; mf < 4; ++mf)
#pragma unroll
    for (int r = 0; r < 4; ++r) {
      float v = val[mf][r];
      v += __shfl_xor(v, 1, 64);
      v += __shfl_xor(v, 2, 64);
      v += __shfl_xor(v, 4, 64);
      v += __shfl_xor(v, 8, 64);
      val[mf][r] = v;
    }
  if ((lane & 15) == 0) {
#pragma unroll
    for (int mf = 0; mf < 4; ++mf)
#pragma unroll
      for (int r = 0; r < 4; ++r)
        atomicAdd(&logits_buf[mbase + mf * 16 + ((lane >> 4) << 2) + r], val[mf][r]);
  }
  __syncthreads();

  if (tid < B_SZ) {
    if (!critic) atomicAdd(&d_out[(size_t)tid * ADIM + col], logits_buf[tid]);
    else         atomicAdd(&d_out[131840 + tid], logits_buf[tid]);
  }
}

// ---------------- Kernel 3: log_softmax / entropy / log_prob ----------------
__global__ __launch_bounds__(256) void kfinal(const int* __restrict__ action,
                                              float* __restrict__ d_out)
{
  const int b = blockIdx.x, t = threadIdx.x;
  const float* lrow = d_out + (size_t)b * ADIM;
  __shared__ float sM[4], sS[4], sT[4];

  const float x0 = lrow[t], x1 = lrow[t + 256];
  float m = fmaxf(x0, x1);
#pragma unroll
  for (int s = 1; s < 64; s <<= 1) m = fmaxf(m, __shfl_xor(m, s, 64));
  const int wv = t >> 6, ln = t & 63;
  if (ln == 0) sM[wv] = m;
  __syncthreads();
  m = fmaxf(fmaxf(sM[0], sM[1]), fmaxf(sM[2], sM[3]));

  const float d0 = x0 - m, d1 = x1 - m;
  const float e0 = expf(d0), e1 = expf(d1);
  float s1 = e0 + e1;
  float s2 = e0 * d0 + e1 * d1;
#pragma unroll
  for (int s = 1; s < 64; s <<= 1) {
    s1 += __shfl_xor(s1, s, 64);
    s2 += __shfl_xor(s2, s, 64);
  }
  if (ln == 0) { sS[wv] = s1; sT[wv] = s2; }
  __syncthreads();
  if (t == 0) {
    const float S = sS[0] + sS[1] + sS[2] + sS[3];
    const float T = sT[0] + sT[1] + sT[2] + sT[3];
    const float lnS = logf(S);
    const int a = action[b];
    d_out[131328 + b] = (lrow[a] - m) - lnS;   // log_prob
    d_out[131584 + b] = lnS - T / S;           // entropy
  }
}

extern "C" void kernel_launch(void* const* d_in, const int* in_sizes, int n_in,
                              void* d_out_v, int out_size, void* d_ws, size_t ws_size,
                              hipStream_t stream) {
  const float* obs   = (const float*)d_in[0];
  const float* task  = (const float*)d_in[1];
  const int*   action= (const int*)  d_in[2];
  const float* we1   = (const float*)d_in[3];
  const float* be1   = (const float*)d_in[4];
  const float* we2   = (const float*)d_in[5];
  const float* be2   = (const float*)d_in[6];
  const float* aw1   = (const float*)d_in[7];
  const float* aw1b  = (const float*)d_in[8];
  const float* aw2   = (const float*)d_in[9];
  const float* aw2b  = (const float*)d_in[10];
  const float* ab1   = (const float*)d_in[11];
  const float* ab1b  = (const float*)d_in[12];
  const float* ab2   = (const float*)d_in[13];
  const float* ab2b  = (const float*)d_in[14];
  const float* cw1   = (const float*)d_in[15];
  const float* cw1b  = (const float*)d_in[16];
  const float* cw2   = (const float*)d_in[17];
  const float* cw2b  = (const float*)d_in[18];
  const float* cb1   = (const float*)d_in[19];
  const float* cb1b  = (const float*)d_in[20];
  const float* cb2   = (const float*)d_in[21];
  const float* cb2b  = (const float*)d_in[22];
  float* out = (float*)d_out_v;
  float* ws_ha = (float*)d_ws;                       // [256][128] f32
  float* ws_hc = ws_ha + 256 * 128;                  // [256][128] f32
  unsigned short* ws_obs = (unsigned short*)(ws_hc + 256 * 128);  // [256][1024] bf16

  kprep<<<256, 128, 0, stream>>>(obs, task, action, we1, be1, we2, be2, aw1, aw1b,
                                 ab1, ab1b, ab2, ab2b, cw1, cw1b, cb1, cb1b,
                                 cb2, cb2b, ws_ha, ws_hc, ws_obs, out);
  // grid: 513 cols (512 actor + critic) x 2 N-halves x 2 K-halves
  khyper<<<513 * 4, 256, 0, stream>>>(ws_obs, aw2, aw2b, cw2, cw2b, ws_ha, ws_hc, out);
  kfinal<<<256, 256, 0, stream>>>(action, out);
}